// Round 12
// baseline (313.317 us; speedup 1.0000x reference)
//
#include <hip/hip_runtime.h>
#include <cstdint>
#include <cstddef>

// SearchTransfer on MI355X (gfx950), fp32.
// B=4, C=64, H=W=64, L=4096, K=9C=576.
//
// Algebra:
//  - lr-patch norm is a positive per-column scalar -> cannot change argmax; dropped.
//  - S[a,b] = sum_{i,j} D[a+d, b+d], D = ref_flat^T * lr_flat (K=64).
//  - E-tile(r1,r2) = x-band of D-tile (register shuffles, R3-validated).
//  - S-tile(y',y) = E(y'-1,y-1)+E(y',y)+E(y'+1,y+1): band v1 (R2/R9-validated).
//
// R11 lesson: K-split gemmE spilled again (VGPR=56, +88MB scratch); its bank
// conflicts (9.4M, identical to R9) are in the READ path, not staging writes.
// This round = EXACT R9 259.7us source with ONE change: nontemporal E stores.
// R8 measured nt write stream at 2.85 TB/s (vs cached 1.63); R9 measured band
// L3-fast when live E = 128 MiB. MALL is memory-side, so nt writes still land
// in it -> band keeps L3 reads. Values identical -> bit-identical output.

#define BATCH 4
#define CCH 64
#define LPIX 4096
typedef unsigned long long u64;
typedef float f4 __attribute__((ext_vector_type(4)));

__device__ __forceinline__ u64 packKey(float v, int idx) {
    unsigned int bits = __float_as_uint(v);
    unsigned int m = (bits & 0x80000000u) ? ~bits : (bits | 0x80000000u);
    // low 32 = ~idx so that larger key == smaller index on equal value
    return ((u64)m << 32) | (unsigned int)(~(unsigned int)idx);
}

// ---- prep: refT[b][p][c] transpose + ssq[b][p] = sum_c ref^2 -------------
__global__ __launch_bounds__(256) void prep_kernel(const float* __restrict__ ref,
                                                   float* __restrict__ refT,
                                                   float* __restrict__ ssq) {
    __shared__ float s[64 * 65];
    __shared__ float part[256];
    int pt = blockIdx.x, b = blockIdx.y, tid = threadIdx.x;
    const float* rb = ref + ((size_t)b * CCH) * LPIX + pt * 64;
    for (int k = 0; k < 16; ++k) {
        int n = tid + 256 * k;           // n = c*64 + p
        int c = n >> 6, p = n & 63;
        s[c * 65 + p] = rb[(size_t)c * LPIX + p];
    }
    __syncthreads();
    {
        int p = tid & 63, g = tid >> 6;
        float acc = 0.f;
        for (int c = g * 16; c < g * 16 + 16; ++c) { float v = s[c * 65 + p]; acc += v * v; }
        part[g * 64 + p] = acc;
    }
    __syncthreads();
    if (tid < 64) {
        float v = part[tid] + part[64 + tid] + part[128 + tid] + part[192 + tid];
        ssq[b * LPIX + pt * 64 + tid] = v;
    }
    float* tb = refT + ((size_t)b * LPIX + pt * 64) * 64;
    for (int k = 0; k < 16; ++k) {
        int n = tid + 256 * k;           // n = p*64 + c
        int p = n >> 6, c = n & 63;
        tb[n] = s[c * 65 + p];
    }
}

// ---- inv[b][p] = 1 / max(sqrt(3x3 box of ssq), 1e-12) --------------------
__global__ __launch_bounds__(256) void invnorm_kernel(const float* __restrict__ ssq,
                                                      float* __restrict__ inv) {
    int t = blockIdx.x * 256 + threadIdx.x;      // over BATCH*LPIX
    int b = t >> 12, p = t & 4095;
    int y = p >> 6, x = p & 63;
    const float* sb = ssq + b * LPIX;
    float n2 = 0.f;
    for (int i = -1; i <= 1; ++i)
        for (int j = -1; j <= 1; ++j) {
            int yy = y + i, xx = x + j;
            if (yy >= 0 && yy < 64 && xx >= 0 && xx < 64) n2 += sb[yy * 64 + xx];
        }
    inv[t] = 1.0f / fmaxf(sqrtf(n2), 1e-12f);
}

// ---- GEMM + x-band epilogue: one wave per 64x64 E-tile (R3/R9-validated) --
// D[x'][x] = sum_c ref[c,r1,x']*lr[c,r2,x]; E[x'][x] = D[x'-1][x-1]+D[x'][x]+D[x'+1][x+1]
__global__ __launch_bounds__(256, 2) void gemmE_kernel(const float* __restrict__ ref,
                                                       const float* __restrict__ lr,
                                                       float* __restrict__ E) {
    __shared__ __align__(16) float As[2 * 4096];   // [h][c][m], m = x' of tile r1=2by+h
    __shared__ __align__(16) float Bs[2 * 4096];   // [h][c][x], tile r2=2bx+h
    int bx = blockIdx.x, by = blockIdx.y, b = blockIdx.z, tid = threadIdx.x;
    const float* Ab = ref + (size_t)b * CCH * LPIX;
    const float* Bb = lr + (size_t)b * CCH * LPIX;
#pragma unroll
    for (int kk = 0; kk < 8; ++kk) {
        int n = tid + 256 * kk;          // 2048 f4: h = n>>10, c = (n>>4)&63, q = n&15
        int h = n >> 10, c = (n >> 4) & 63, q = n & 15;
        *(float4*)&As[h * 4096 + c * 64 + 4 * q] =
            *(const float4*)&Ab[(size_t)c * LPIX + (2 * by + h) * 64 + 4 * q];
        *(float4*)&Bs[h * 4096 + c * 64 + 4 * q] =
            *(const float4*)&Bb[(size_t)c * LPIX + (2 * bx + h) * 64 + 4 * q];
    }
    __syncthreads();
    int w = tid >> 6, lane = tid & 63, rg = lane >> 3, cg = lane & 7;
    const float* Ap = As + (w >> 1) * 4096 + rg * 8;
    const float* Bp = Bs + (w & 1) * 4096 + cg * 8;
    float acc[8][8] = {};
#pragma unroll 4
    for (int k = 0; k < 64; ++k) {
        float4 a0 = *(const float4*)(Ap + k * 64);
        float4 a1 = *(const float4*)(Ap + k * 64 + 4);
        float4 b0 = *(const float4*)(Bp + k * 64);
        float4 b1 = *(const float4*)(Bp + k * 64 + 4);
        float av[8] = {a0.x, a0.y, a0.z, a0.w, a1.x, a1.y, a1.z, a1.w};
        float bv[8] = {b0.x, b0.y, b0.z, b0.w, b1.x, b1.y, b1.z, b1.w};
#pragma unroll
        for (int i = 0; i < 8; ++i)
#pragma unroll
            for (int j = 0; j < 8; ++j) acc[i][j] = fmaf(av[i], bv[j], acc[i][j]);
    }
    // x-band epilogue in registers: E[r][c] = D[r-1][c-1] + D[r][c] + D[r+1][c+1]
    float up[7], lf[7], dn[8], rt[8], um, dpc;
#pragma unroll
    for (int t = 0; t < 7; ++t) up[t] = __shfl(acc[7][t], lane - 8, 64);
    um = __shfl(acc[7][7], lane - 9, 64);
#pragma unroll
    for (int t = 0; t < 7; ++t) lf[t] = __shfl(acc[t][7], lane - 1, 64);
#pragma unroll
    for (int t = 1; t < 8; ++t) dn[t] = __shfl(acc[0][t], lane + 8, 64);
    dpc = __shfl(acc[0][0], lane + 9, 64);
#pragma unroll
    for (int t = 1; t < 8; ++t) rt[t] = __shfl(acc[t][0], lane + 1, 64);

    int r1 = 2 * by + (w >> 1), r2 = 2 * bx + (w & 1);
    float* Et = E + ((size_t)b << 24) + ((size_t)((r1 << 6) + r2) << 12) + (rg * 8) * 64 + cg * 8;
    bool rgt = rg > 0, rlt = rg < 7, cgt = cg > 0, clt = cg < 7;
#pragma unroll
    for (int i = 0; i < 8; ++i) {
        float e[8];
#pragma unroll
        for (int j = 0; j < 8; ++j) {
            float dm, dpv;
            if (i >= 1) dm = (j >= 1) ? acc[i - 1][j - 1] : (cgt ? lf[i - 1] : 0.f);
            else        dm = rgt ? ((j >= 1) ? up[j - 1] : (cgt ? um : 0.f)) : 0.f;
            if (i <= 6) dpv = (j <= 6) ? acc[i + 1][j + 1] : (clt ? rt[i + 1] : 0.f);
            else        dpv = rlt ? ((j <= 6) ? dn[j + 1] : (clt ? dpc : 0.f)) : 0.f;
            e[j] = dm + acc[i][j] + dpv;
        }
        f4 o0 = {e[0], e[1], e[2], e[3]};
        f4 o1 = {e[4], e[5], e[6], e[7]};
        __builtin_nontemporal_store(o0, (f4*)(Et + i * 64));      // nt stream (2.85 TB/s, R8)
        __builtin_nontemporal_store(o1, (f4*)(Et + i * 64 + 4));
    }
}

// ---- band v1: diagonal-segment sweep, register ring of 3 E-tiles (R9) ----
// block (bx=segment, by=k+63, bz=batch); S-tile(y+k, y) = Ea+Eb+Ec elementwise
__global__ __launch_bounds__(256) void band_kernel(const float* __restrict__ E,
                                                   const float* __restrict__ inv,
                                                   u64* __restrict__ packed) {
    __shared__ u64 red[16 * 65];
    int b = blockIdx.z;
    int k = (int)blockIdx.y - 63;
    int t_lo = k < 0 ? -k : 0;
    int t_hi = 64 - (k > 0 ? k : 0);
    int y0 = t_lo + (int)blockIdx.x * 16;
    if (y0 >= t_hi) return;
    int y1 = y0 + 16 < t_hi ? y0 + 16 : t_hi;
    const float* Ebase = E + ((size_t)b << 24);
    const float* invb = inv + b * LPIX;
    u64* pkb = packed + (size_t)b * LPIX;
    int tid = threadIdx.x;
    int c4 = tid & 15, s = tid >> 4;     // cols 4*c4.., x' strata s+16i

    float4 Ea[4], Eb[4], Ec[4];
    auto LOADT = [&](float4* T, int t) {
        if (t >= t_lo && t < t_hi) {
            const float4* tp = (const float4*)(Ebase + ((size_t)(((t + k) << 6) + t) << 12));
#pragma unroll
            for (int i = 0; i < 4; ++i) T[i] = tp[tid + 256 * i];
        } else {
#pragma unroll
            for (int i = 0; i < 4; ++i) T[i] = make_float4(0.f, 0.f, 0.f, 0.f);
        }
    };
    LOADT(Ea, y0 - 1); LOADT(Eb, y0); LOADT(Ec, y0 + 1);

    for (int y = y0; y < y1; ++y) {
        int yprow = (y + k) << 6;        // y' * 64
        u64 kc0 = 0, kc1 = 0, kc2 = 0, kc3 = 0;
#pragma unroll
        for (int i = 0; i < 4; ++i) {
            int xr = s + 16 * i;         // x'
            float iv = invb[yprow + xr];
            int idx = yprow + xr;        // p' = y'*64 + x'
            float vx = (Ea[i].x + Eb[i].x + Ec[i].x) * iv;
            float vy = (Ea[i].y + Eb[i].y + Ec[i].y) * iv;
            float vz = (Ea[i].z + Eb[i].z + Ec[i].z) * iv;
            float vw = (Ea[i].w + Eb[i].w + Ec[i].w) * iv;
            u64 t0 = packKey(vx, idx); kc0 = kc0 > t0 ? kc0 : t0;
            u64 t1 = packKey(vy, idx); kc1 = kc1 > t1 ? kc1 : t1;
            u64 t2 = packKey(vz, idx); kc2 = kc2 > t2 ? kc2 : t2;
            u64 t3 = packKey(vw, idx); kc3 = kc3 > t3 ? kc3 : t3;
        }
        red[s * 65 + 4 * c4 + 0] = kc0;
        red[s * 65 + 4 * c4 + 1] = kc1;
        red[s * 65 + 4 * c4 + 2] = kc2;
        red[s * 65 + 4 * c4 + 3] = kc3;
        __syncthreads();
        if (tid < 64) {
            u64 m = red[tid];
#pragma unroll
            for (int ss = 1; ss < 16; ++ss) {
                u64 v = red[ss * 65 + tid];
                m = m > v ? m : v;
            }
            atomicMax(&pkb[(y << 6) + tid], m);
        }
        __syncthreads();
        if (y + 1 < y1) {
            float4 En[4];
            LOADT(En, y + 2);
#pragma unroll
            for (int i = 0; i < 4; ++i) { Ea[i] = Eb[i]; Eb[i] = Ec[i]; Ec[i] = En[i]; }
        }
    }
}

// ---- gather + fold: one wave per output pixel ----------------------------
__global__ __launch_bounds__(256) void gather_kernel(const u64* __restrict__ packed,
                                                     const float* __restrict__ refT,
                                                     float* __restrict__ Tt) {
    int b = blockIdx.y;
    int wave = threadIdx.x >> 6, lane = threadIdx.x & 63;
    int p = blockIdx.x * 4 + wave;       // 0..4095
    int py = p >> 6, px = p & 63;
    const u64* pk = packed + (size_t)b * LPIX;
    const float* rT = refT + (size_t)b * LPIX * 64;
    float acc = 0.f;
#pragma unroll
    for (int i = 0; i < 3; ++i)
#pragma unroll
        for (int j = 0; j < 3; ++j) {
            int qy = py + 1 - i, qx = px + 1 - j;
            if ((unsigned)qy >= 64u || (unsigned)qx >= 64u) continue;
            int aidx = (int)(~(unsigned int)pk[qy * 64 + qx]);
            int ry = (aidx >> 6) + i - 1, rx = (aidx & 63) + j - 1;
            if ((unsigned)ry >= 64u || (unsigned)rx >= 64u) continue;
            acc += rT[(size_t)(ry * 64 + rx) * 64 + lane];
        }
    Tt[((size_t)b * LPIX + p) * 64 + lane] = acc;
}

// ---- 1x1 conv: z[b][co][p] = w1[co][0:64]*lr + w1[co][64:128]*T + b1 -----
#define XST 36
__global__ __launch_bounds__(256) void conv1_kernel(const float* __restrict__ lr,
                                                    const float* __restrict__ Tt,
                                                    const float* __restrict__ w1,
                                                    const float* __restrict__ b1,
                                                    float* __restrict__ z) {
    __shared__ __align__(16) float xs[128 * XST];
    __shared__ __align__(16) float wsm[64 * 128];
    int pt = blockIdx.x, b = blockIdx.y, tid = threadIdx.x;
    for (int k = 0; k < 8; ++k) {
        int n = tid + 256 * k;           // 2048 float4s of w1
        *(float4*)&wsm[4 * n] = *(const float4*)&w1[4 * n];
    }
    const float* lrb = lr + (size_t)b * CCH * LPIX + pt * 32;
    for (int k = 0; k < 2; ++k) {
        int n = tid + 256 * k;           // 512 f4: c = n>>3, q = n&7
        int c = n >> 3, q = n & 7;
        *(float4*)&xs[c * XST + 4 * q] = *(const float4*)&lrb[(size_t)c * LPIX + 4 * q];
    }
    const float* Tb = Tt + ((size_t)b * LPIX + pt * 32) * 64;
    for (int k = 0; k < 2; ++k) {
        int n = tid + 256 * k;           // 512 f4: p = n>>4, cq = n&15
        int p = n >> 4, cq = n & 15;
        float4 v = *(const float4*)&Tb[p * 64 + 4 * cq];
        xs[(64 + 4 * cq + 0) * XST + p] = v.x;
        xs[(64 + 4 * cq + 1) * XST + p] = v.y;
        xs[(64 + 4 * cq + 2) * XST + p] = v.z;
        xs[(64 + 4 * cq + 3) * XST + p] = v.w;
    }
    __syncthreads();
    int p = tid & 31, g = tid >> 5;      // g: 8 groups of 8 output channels
    float acc[8];
#pragma unroll
    for (int t = 0; t < 8; ++t) acc[t] = b1[g * 8 + t];
    for (int c = 0; c < 128; ++c) {
        float xv = xs[c * XST + p];
#pragma unroll
        for (int t = 0; t < 8; ++t) acc[t] = fmaf(wsm[(g * 8 + t) * 128 + c], xv, acc[t]);
    }
    float* zb = z + (size_t)b * CCH * LPIX + pt * 32;
#pragma unroll
    for (int t = 0; t < 8; ++t) zb[(size_t)(g * 8 + t) * LPIX + p] = acc[t];
}

// ---- depthwise 3x3 + bias + relu -> out ----------------------------------
__global__ __launch_bounds__(256) void dw_kernel(const float* __restrict__ z,
                                                 const float* __restrict__ wd,
                                                 const float* __restrict__ bd,
                                                 float* __restrict__ out) {
    __shared__ __align__(16) float zs[4096];
    int c = blockIdx.x, b = blockIdx.y, tid = threadIdx.x;
    const float* zb = z + ((size_t)b * CCH + c) * LPIX;
    for (int k = 0; k < 4; ++k) {
        int n = tid + 256 * k;
        *(float4*)&zs[4 * n] = *(const float4*)&zb[4 * n];
    }
    __syncthreads();
    float w[9];
#pragma unroll
    for (int t = 0; t < 9; ++t) w[t] = wd[c * 9 + t];
    float bias = bd[c];
    float* ob = out + ((size_t)b * CCH + c) * LPIX;
    for (int s = 0; s < 16; ++s) {
        int p = tid + 256 * s;
        int y = p >> 6, x = p & 63;
        float acc = bias;
#pragma unroll
        for (int i = 0; i < 3; ++i) {
            int yy = y + i - 1;
            if ((unsigned)yy >= 64u) continue;
#pragma unroll
            for (int j = 0; j < 3; ++j) {
                int xx = x + j - 1;
                if ((unsigned)xx >= 64u) continue;
                acc = fmaf(zs[yy * 64 + xx], w[i * 3 + j], acc);
            }
        }
        ob[p] = fmaxf(acc, 0.f);
    }
}

extern "C" void kernel_launch(void* const* d_in, const int* in_sizes, int n_in,
                              void* d_out, int out_size, void* d_ws, size_t ws_size,
                              hipStream_t stream) {
    const float* lr  = (const float*)d_in[0];
    const float* ref = (const float*)d_in[1];
    const float* w1  = (const float*)d_in[2];
    const float* b1  = (const float*)d_in[3];
    const float* wd  = (const float*)d_in[4];
    const float* bd  = (const float*)d_in[5];
    float* out = (float*)d_out;

    float* ws = (float*)d_ws;
    float* refT = ws;                                   // 1,048,576 f
    float* ssq  = refT + (size_t)1048576;               //    16,384 f
    float* inv  = ssq + 16384;                          //    16,384 f
    u64* packed = (u64*)(inv + 16384);                  //    16,384 u64
    float* Tt = (float*)(packed + 16384);               // 1,048,576 f
    float* z  = Tt + (size_t)1048576;                   // 1,048,576 f
    float* E  = z + (size_t)1048576;                    // NB * 16,777,216 f (reused)

    const size_t base = 12845056ull;                    // bytes before E
    const size_t per  = 67108864ull;                    // E bytes per batch
    // NB=2 keeps live E at 128 MiB -> L3-resident for band reads (R9-validated).
    int NB = (ws_size >= base + 2 * per) ? 2 : 1;

    hipMemsetAsync(packed, 0, (size_t)BATCH * LPIX * sizeof(u64), stream);
    prep_kernel<<<dim3(64, BATCH), 256, 0, stream>>>(ref, refT, ssq);
    invnorm_kernel<<<dim3(64), 256, 0, stream>>>(ssq, inv);
    for (int b0 = 0; b0 < BATCH; b0 += NB) {
        gemmE_kernel<<<dim3(32, 32, NB), 256, 0, stream>>>(
            ref + (size_t)b0 * CCH * LPIX, lr + (size_t)b0 * CCH * LPIX, E);
        band_kernel<<<dim3(4, 127, NB), 256, 0, stream>>>(
            E, inv + (size_t)b0 * LPIX, packed + (size_t)b0 * LPIX);
    }
    gather_kernel<<<dim3(1024, BATCH), 256, 0, stream>>>(packed, refT, Tt);
    conv1_kernel<<<dim3(128, BATCH), 256, 0, stream>>>(lr, Tt, w1, b1, z);
    dw_kernel<<<dim3(64, BATCH), 256, 0, stream>>>(z, wd, bd, out);
}

// Round 13
// 259.278 us; speedup vs baseline: 1.2084x; 1.2084x over previous
//
#include <hip/hip_runtime.h>
#include <cstdint>
#include <cstddef>

// SearchTransfer on MI355X (gfx950), fp32.  == EXACT R9 configuration (best: 259.7us) ==
// B=4, C=64, H=W=64, L=4096, K=9C=576.
//
// Algebra:
//  - lr-patch norm is a positive per-column scalar -> cannot change argmax; dropped.
//  - S[a,b] = sum_{i,j} D[a+d, b+d], D = ref_flat^T * lr_flat (K=64).
//  - E-tile(r1,r2) = x-band of D-tile (register shuffles, R3-validated).
//  - S-tile(y',y) = E(y'-1,y-1)+E(y',y)+E(y'+1,y+1): band v1 (R2/R9-validated).
//
// Roofline accounting (measured):
//  - E write stream: 1.45-1.73 TB/s across 3 kernel structures and 15-33% occ
//    (R2/R3/R8/R9/R12) -> platform write ceiling. nt vs cached: no gain (R12).
//  - band E reads: 4.3 TB/s when live E = 128 MiB (L3/MALL-resident, R9).
//  - per chunk: 128 MiB write @1.6 (82us, compute hidden) + read @4.3 (30us).
//  - 2 chunks + ~35us tail = ~259us == R9 measurement. At ceiling.

#define BATCH 4
#define CCH 64
#define LPIX 4096
typedef unsigned long long u64;

__device__ __forceinline__ u64 packKey(float v, int idx) {
    unsigned int bits = __float_as_uint(v);
    unsigned int m = (bits & 0x80000000u) ? ~bits : (bits | 0x80000000u);
    // low 32 = ~idx so that larger key == smaller index on equal value
    return ((u64)m << 32) | (unsigned int)(~(unsigned int)idx);
}

// ---- prep: refT[b][p][c] transpose + ssq[b][p] = sum_c ref^2 -------------
__global__ __launch_bounds__(256) void prep_kernel(const float* __restrict__ ref,
                                                   float* __restrict__ refT,
                                                   float* __restrict__ ssq) {
    __shared__ float s[64 * 65];
    __shared__ float part[256];
    int pt = blockIdx.x, b = blockIdx.y, tid = threadIdx.x;
    const float* rb = ref + ((size_t)b * CCH) * LPIX + pt * 64;
    for (int k = 0; k < 16; ++k) {
        int n = tid + 256 * k;           // n = c*64 + p
        int c = n >> 6, p = n & 63;
        s[c * 65 + p] = rb[(size_t)c * LPIX + p];
    }
    __syncthreads();
    {
        int p = tid & 63, g = tid >> 6;
        float acc = 0.f;
        for (int c = g * 16; c < g * 16 + 16; ++c) { float v = s[c * 65 + p]; acc += v * v; }
        part[g * 64 + p] = acc;
    }
    __syncthreads();
    if (tid < 64) {
        float v = part[tid] + part[64 + tid] + part[128 + tid] + part[192 + tid];
        ssq[b * LPIX + pt * 64 + tid] = v;
    }
    float* tb = refT + ((size_t)b * LPIX + pt * 64) * 64;
    for (int k = 0; k < 16; ++k) {
        int n = tid + 256 * k;           // n = p*64 + c
        int p = n >> 6, c = n & 63;
        tb[n] = s[c * 65 + p];
    }
}

// ---- inv[b][p] = 1 / max(sqrt(3x3 box of ssq), 1e-12) --------------------
__global__ __launch_bounds__(256) void invnorm_kernel(const float* __restrict__ ssq,
                                                      float* __restrict__ inv) {
    int t = blockIdx.x * 256 + threadIdx.x;      // over BATCH*LPIX
    int b = t >> 12, p = t & 4095;
    int y = p >> 6, x = p & 63;
    const float* sb = ssq + b * LPIX;
    float n2 = 0.f;
    for (int i = -1; i <= 1; ++i)
        for (int j = -1; j <= 1; ++j) {
            int yy = y + i, xx = x + j;
            if (yy >= 0 && yy < 64 && xx >= 0 && xx < 64) n2 += sb[yy * 64 + xx];
        }
    inv[t] = 1.0f / fmaxf(sqrtf(n2), 1e-12f);
}

// ---- GEMM + x-band epilogue: one wave per 64x64 E-tile (R3/R9-validated) --
// D[x'][x] = sum_c ref[c,r1,x']*lr[c,r2,x]; E[x'][x] = D[x'-1][x-1]+D[x'][x]+D[x'+1][x+1]
__global__ __launch_bounds__(256, 2) void gemmE_kernel(const float* __restrict__ ref,
                                                       const float* __restrict__ lr,
                                                       float* __restrict__ E) {
    __shared__ __align__(16) float As[2 * 4096];   // [h][c][m], m = x' of tile r1=2by+h
    __shared__ __align__(16) float Bs[2 * 4096];   // [h][c][x], tile r2=2bx+h
    int bx = blockIdx.x, by = blockIdx.y, b = blockIdx.z, tid = threadIdx.x;
    const float* Ab = ref + (size_t)b * CCH * LPIX;
    const float* Bb = lr + (size_t)b * CCH * LPIX;
#pragma unroll
    for (int kk = 0; kk < 8; ++kk) {
        int n = tid + 256 * kk;          // 2048 f4: h = n>>10, c = (n>>4)&63, q = n&15
        int h = n >> 10, c = (n >> 4) & 63, q = n & 15;
        *(float4*)&As[h * 4096 + c * 64 + 4 * q] =
            *(const float4*)&Ab[(size_t)c * LPIX + (2 * by + h) * 64 + 4 * q];
        *(float4*)&Bs[h * 4096 + c * 64 + 4 * q] =
            *(const float4*)&Bb[(size_t)c * LPIX + (2 * bx + h) * 64 + 4 * q];
    }
    __syncthreads();
    int w = tid >> 6, lane = tid & 63, rg = lane >> 3, cg = lane & 7;
    const float* Ap = As + (w >> 1) * 4096 + rg * 8;
    const float* Bp = Bs + (w & 1) * 4096 + cg * 8;
    float acc[8][8] = {};
#pragma unroll 4
    for (int k = 0; k < 64; ++k) {
        float4 a0 = *(const float4*)(Ap + k * 64);
        float4 a1 = *(const float4*)(Ap + k * 64 + 4);
        float4 b0 = *(const float4*)(Bp + k * 64);
        float4 b1 = *(const float4*)(Bp + k * 64 + 4);
        float av[8] = {a0.x, a0.y, a0.z, a0.w, a1.x, a1.y, a1.z, a1.w};
        float bv[8] = {b0.x, b0.y, b0.z, b0.w, b1.x, b1.y, b1.z, b1.w};
#pragma unroll
        for (int i = 0; i < 8; ++i)
#pragma unroll
            for (int j = 0; j < 8; ++j) acc[i][j] = fmaf(av[i], bv[j], acc[i][j]);
    }
    // x-band epilogue in registers: E[r][c] = D[r-1][c-1] + D[r][c] + D[r+1][c+1]
    float up[7], lf[7], dn[8], rt[8], um, dpc;
#pragma unroll
    for (int t = 0; t < 7; ++t) up[t] = __shfl(acc[7][t], lane - 8, 64);
    um = __shfl(acc[7][7], lane - 9, 64);
#pragma unroll
    for (int t = 0; t < 7; ++t) lf[t] = __shfl(acc[t][7], lane - 1, 64);
#pragma unroll
    for (int t = 1; t < 8; ++t) dn[t] = __shfl(acc[0][t], lane + 8, 64);
    dpc = __shfl(acc[0][0], lane + 9, 64);
#pragma unroll
    for (int t = 1; t < 8; ++t) rt[t] = __shfl(acc[t][0], lane + 1, 64);

    int r1 = 2 * by + (w >> 1), r2 = 2 * bx + (w & 1);
    float* Et = E + ((size_t)b << 24) + ((size_t)((r1 << 6) + r2) << 12) + (rg * 8) * 64 + cg * 8;
    bool rgt = rg > 0, rlt = rg < 7, cgt = cg > 0, clt = cg < 7;
#pragma unroll
    for (int i = 0; i < 8; ++i) {
        float e[8];
#pragma unroll
        for (int j = 0; j < 8; ++j) {
            float dm, dpv;
            if (i >= 1) dm = (j >= 1) ? acc[i - 1][j - 1] : (cgt ? lf[i - 1] : 0.f);
            else        dm = rgt ? ((j >= 1) ? up[j - 1] : (cgt ? um : 0.f)) : 0.f;
            if (i <= 6) dpv = (j <= 6) ? acc[i + 1][j + 1] : (clt ? rt[i + 1] : 0.f);
            else        dpv = rlt ? ((j <= 6) ? dn[j + 1] : (clt ? dpc : 0.f)) : 0.f;
            e[j] = dm + acc[i][j] + dpv;
        }
        *(float4*)(Et + i * 64)     = make_float4(e[0], e[1], e[2], e[3]);
        *(float4*)(Et + i * 64 + 4) = make_float4(e[4], e[5], e[6], e[7]);
    }
}

// ---- band v1: diagonal-segment sweep, register ring of 3 E-tiles (R9) ----
// block (bx=segment, by=k+63, bz=batch); S-tile(y+k, y) = Ea+Eb+Ec elementwise
__global__ __launch_bounds__(256) void band_kernel(const float* __restrict__ E,
                                                   const float* __restrict__ inv,
                                                   u64* __restrict__ packed) {
    __shared__ u64 red[16 * 65];
    int b = blockIdx.z;
    int k = (int)blockIdx.y - 63;
    int t_lo = k < 0 ? -k : 0;
    int t_hi = 64 - (k > 0 ? k : 0);
    int y0 = t_lo + (int)blockIdx.x * 16;
    if (y0 >= t_hi) return;
    int y1 = y0 + 16 < t_hi ? y0 + 16 : t_hi;
    const float* Ebase = E + ((size_t)b << 24);
    const float* invb = inv + b * LPIX;
    u64* pkb = packed + (size_t)b * LPIX;
    int tid = threadIdx.x;
    int c4 = tid & 15, s = tid >> 4;     // cols 4*c4.., x' strata s+16i

    float4 Ea[4], Eb[4], Ec[4];
    auto LOADT = [&](float4* T, int t) {
        if (t >= t_lo && t < t_hi) {
            const float4* tp = (const float4*)(Ebase + ((size_t)(((t + k) << 6) + t) << 12));
#pragma unroll
            for (int i = 0; i < 4; ++i) T[i] = tp[tid + 256 * i];
        } else {
#pragma unroll
            for (int i = 0; i < 4; ++i) T[i] = make_float4(0.f, 0.f, 0.f, 0.f);
        }
    };
    LOADT(Ea, y0 - 1); LOADT(Eb, y0); LOADT(Ec, y0 + 1);

    for (int y = y0; y < y1; ++y) {
        int yprow = (y + k) << 6;        // y' * 64
        u64 kc0 = 0, kc1 = 0, kc2 = 0, kc3 = 0;
#pragma unroll
        for (int i = 0; i < 4; ++i) {
            int xr = s + 16 * i;         // x'
            float iv = invb[yprow + xr];
            int idx = yprow + xr;        // p' = y'*64 + x'
            float vx = (Ea[i].x + Eb[i].x + Ec[i].x) * iv;
            float vy = (Ea[i].y + Eb[i].y + Ec[i].y) * iv;
            float vz = (Ea[i].z + Eb[i].z + Ec[i].z) * iv;
            float vw = (Ea[i].w + Eb[i].w + Ec[i].w) * iv;
            u64 t0 = packKey(vx, idx); kc0 = kc0 > t0 ? kc0 : t0;
            u64 t1 = packKey(vy, idx); kc1 = kc1 > t1 ? kc1 : t1;
            u64 t2 = packKey(vz, idx); kc2 = kc2 > t2 ? kc2 : t2;
            u64 t3 = packKey(vw, idx); kc3 = kc3 > t3 ? kc3 : t3;
        }
        red[s * 65 + 4 * c4 + 0] = kc0;
        red[s * 65 + 4 * c4 + 1] = kc1;
        red[s * 65 + 4 * c4 + 2] = kc2;
        red[s * 65 + 4 * c4 + 3] = kc3;
        __syncthreads();
        if (tid < 64) {
            u64 m = red[tid];
#pragma unroll
            for (int ss = 1; ss < 16; ++ss) {
                u64 v = red[ss * 65 + tid];
                m = m > v ? m : v;
            }
            atomicMax(&pkb[(y << 6) + tid], m);
        }
        __syncthreads();
        if (y + 1 < y1) {
            float4 En[4];
            LOADT(En, y + 2);
#pragma unroll
            for (int i = 0; i < 4; ++i) { Ea[i] = Eb[i]; Eb[i] = Ec[i]; Ec[i] = En[i]; }
        }
    }
}

// ---- gather + fold: one wave per output pixel ----------------------------
__global__ __launch_bounds__(256) void gather_kernel(const u64* __restrict__ packed,
                                                     const float* __restrict__ refT,
                                                     float* __restrict__ Tt) {
    int b = blockIdx.y;
    int wave = threadIdx.x >> 6, lane = threadIdx.x & 63;
    int p = blockIdx.x * 4 + wave;       // 0..4095
    int py = p >> 6, px = p & 63;
    const u64* pk = packed + (size_t)b * LPIX;
    const float* rT = refT + (size_t)b * LPIX * 64;
    float acc = 0.f;
#pragma unroll
    for (int i = 0; i < 3; ++i)
#pragma unroll
        for (int j = 0; j < 3; ++j) {
            int qy = py + 1 - i, qx = px + 1 - j;
            if ((unsigned)qy >= 64u || (unsigned)qx >= 64u) continue;
            int aidx = (int)(~(unsigned int)pk[qy * 64 + qx]);
            int ry = (aidx >> 6) + i - 1, rx = (aidx & 63) + j - 1;
            if ((unsigned)ry >= 64u || (unsigned)rx >= 64u) continue;
            acc += rT[(size_t)(ry * 64 + rx) * 64 + lane];
        }
    Tt[((size_t)b * LPIX + p) * 64 + lane] = acc;
}

// ---- 1x1 conv: z[b][co][p] = w1[co][0:64]*lr + w1[co][64:128]*T + b1 -----
#define XST 36
__global__ __launch_bounds__(256) void conv1_kernel(const float* __restrict__ lr,
                                                    const float* __restrict__ Tt,
                                                    const float* __restrict__ w1,
                                                    const float* __restrict__ b1,
                                                    float* __restrict__ z) {
    __shared__ __align__(16) float xs[128 * XST];
    __shared__ __align__(16) float wsm[64 * 128];
    int pt = blockIdx.x, b = blockIdx.y, tid = threadIdx.x;
    for (int k = 0; k < 8; ++k) {
        int n = tid + 256 * k;           // 2048 float4s of w1
        *(float4*)&wsm[4 * n] = *(const float4*)&w1[4 * n];
    }
    const float* lrb = lr + (size_t)b * CCH * LPIX + pt * 32;
    for (int k = 0; k < 2; ++k) {
        int n = tid + 256 * k;           // 512 f4: c = n>>3, q = n&7
        int c = n >> 3, q = n & 7;
        *(float4*)&xs[c * XST + 4 * q] = *(const float4*)&lrb[(size_t)c * LPIX + 4 * q];
    }
    const float* Tb = Tt + ((size_t)b * LPIX + pt * 32) * 64;
    for (int k = 0; k < 2; ++k) {
        int n = tid + 256 * k;           // 512 f4: p = n>>4, cq = n&15
        int p = n >> 4, cq = n & 15;
        float4 v = *(const float4*)&Tb[p * 64 + 4 * cq];
        xs[(64 + 4 * cq + 0) * XST + p] = v.x;
        xs[(64 + 4 * cq + 1) * XST + p] = v.y;
        xs[(64 + 4 * cq + 2) * XST + p] = v.z;
        xs[(64 + 4 * cq + 3) * XST + p] = v.w;
    }
    __syncthreads();
    int p = tid & 31, g = tid >> 5;      // g: 8 groups of 8 output channels
    float acc[8];
#pragma unroll
    for (int t = 0; t < 8; ++t) acc[t] = b1[g * 8 + t];
    for (int c = 0; c < 128; ++c) {
        float xv = xs[c * XST + p];
#pragma unroll
        for (int t = 0; t < 8; ++t) acc[t] = fmaf(wsm[(g * 8 + t) * 128 + c], xv, acc[t]);
    }
    float* zb = z + (size_t)b * CCH * LPIX + pt * 32;
#pragma unroll
    for (int t = 0; t < 8; ++t) zb[(size_t)(g * 8 + t) * LPIX + p] = acc[t];
}

// ---- depthwise 3x3 + bias + relu -> out ----------------------------------
__global__ __launch_bounds__(256) void dw_kernel(const float* __restrict__ z,
                                                 const float* __restrict__ wd,
                                                 const float* __restrict__ bd,
                                                 float* __restrict__ out) {
    __shared__ __align__(16) float zs[4096];
    int c = blockIdx.x, b = blockIdx.y, tid = threadIdx.x;
    const float* zb = z + ((size_t)b * CCH + c) * LPIX;
    for (int k = 0; k < 4; ++k) {
        int n = tid + 256 * k;
        *(float4*)&zs[4 * n] = *(const float4*)&zb[4 * n];
    }
    __syncthreads();
    float w[9];
#pragma unroll
    for (int t = 0; t < 9; ++t) w[t] = wd[c * 9 + t];
    float bias = bd[c];
    float* ob = out + ((size_t)b * CCH + c) * LPIX;
    for (int s = 0; s < 16; ++s) {
        int p = tid + 256 * s;
        int y = p >> 6, x = p & 63;
        float acc = bias;
#pragma unroll
        for (int i = 0; i < 3; ++i) {
            int yy = y + i - 1;
            if ((unsigned)yy >= 64u) continue;
#pragma unroll
            for (int j = 0; j < 3; ++j) {
                int xx = x + j - 1;
                if ((unsigned)xx >= 64u) continue;
                acc = fmaf(zs[yy * 64 + xx], w[i * 3 + j], acc);
            }
        }
        ob[p] = fmaxf(acc, 0.f);
    }
}

extern "C" void kernel_launch(void* const* d_in, const int* in_sizes, int n_in,
                              void* d_out, int out_size, void* d_ws, size_t ws_size,
                              hipStream_t stream) {
    const float* lr  = (const float*)d_in[0];
    const float* ref = (const float*)d_in[1];
    const float* w1  = (const float*)d_in[2];
    const float* b1  = (const float*)d_in[3];
    const float* wd  = (const float*)d_in[4];
    const float* bd  = (const float*)d_in[5];
    float* out = (float*)d_out;

    float* ws = (float*)d_ws;
    float* refT = ws;                                   // 1,048,576 f
    float* ssq  = refT + (size_t)1048576;               //    16,384 f
    float* inv  = ssq + 16384;                          //    16,384 f
    u64* packed = (u64*)(inv + 16384);                  //    16,384 u64
    float* Tt = (float*)(packed + 16384);               // 1,048,576 f
    float* z  = Tt + (size_t)1048576;                   // 1,048,576 f
    float* E  = z + (size_t)1048576;                    // NB * 16,777,216 f (reused)

    const size_t base = 12845056ull;                    // bytes before E
    const size_t per  = 67108864ull;                    // E bytes per batch
    // NB=2 keeps live E at 128 MiB -> L3-resident for band reads (R9-validated).
    int NB = (ws_size >= base + 2 * per) ? 2 : 1;

    hipMemsetAsync(packed, 0, (size_t)BATCH * LPIX * sizeof(u64), stream);
    prep_kernel<<<dim3(64, BATCH), 256, 0, stream>>>(ref, refT, ssq);
    invnorm_kernel<<<dim3(64), 256, 0, stream>>>(ssq, inv);
    for (int b0 = 0; b0 < BATCH; b0 += NB) {
        gemmE_kernel<<<dim3(32, 32, NB), 256, 0, stream>>>(
            ref + (size_t)b0 * CCH * LPIX, lr + (size_t)b0 * CCH * LPIX, E);
        band_kernel<<<dim3(4, 127, NB), 256, 0, stream>>>(
            E, inv + (size_t)b0 * LPIX, packed + (size_t)b0 * LPIX);
    }
    gather_kernel<<<dim3(1024, BATCH), 256, 0, stream>>>(packed, refT, Tt);
    conv1_kernel<<<dim3(128, BATCH), 256, 0, stream>>>(lr, Tt, w1, b1, z);
    dw_kernel<<<dim3(64, BATCH), 256, 0, stream>>>(z, wd, bd, out);
}

// Round 14
// 255.009 us; speedup vs baseline: 1.2286x; 1.0167x over previous
//
#include <hip/hip_runtime.h>
#include <cstdint>
#include <cstddef>

// SearchTransfer on MI355X (gfx950), fp32.
// B=4, C=64, H=W=64, L=4096, K=9C=576.
//
// Algebra:
//  - lr-patch norm is a positive per-column scalar -> cannot change argmax; dropped.
//  - S[a,b] = sum_{i,j} D[a+d, b+d], D = ref_flat^T * lr_flat (K=64).
//  - E-tile(r1,r2) = x-band of D-tile (register shuffles, R3-validated).
//  - S-tile(y',y) = E(y'-1,y-1)+E(y',y)+E(y'+1,y+1): band v1 (R2/R9-validated).
//
// R13: R9 reproduced (259.3us; gemmE 82us/chunk @1.63 TB/s writes, 8 waves/CU).
// Open question: is 1.6 TB/s a fabric write ceiling or a store-concurrency
// limit? m13 copy (6.29 TB/s total) implies ~3.1 TB/s write stream at high
// occupancy. This round's single change: gemmE stages K in two 32-channel
// halves through a 32 KiB LDS buffer (3 barriers, no persistent prefetch regs,
// channel order 0..63 unchanged -> bit-identical E). LDS 64->32 KiB raises
// residency 2 -> up to 5 blocks/CU = 2.5x concurrent store drains.
// Null result (gemmE ~82us at higher occupancy) => fabric ceiling => roofline.

#define BATCH 4
#define CCH 64
#define LPIX 4096
typedef unsigned long long u64;

__device__ __forceinline__ u64 packKey(float v, int idx) {
    unsigned int bits = __float_as_uint(v);
    unsigned int m = (bits & 0x80000000u) ? ~bits : (bits | 0x80000000u);
    // low 32 = ~idx so that larger key == smaller index on equal value
    return ((u64)m << 32) | (unsigned int)(~(unsigned int)idx);
}

// ---- prep: refT[b][p][c] transpose + ssq[b][p] = sum_c ref^2 -------------
__global__ __launch_bounds__(256) void prep_kernel(const float* __restrict__ ref,
                                                   float* __restrict__ refT,
                                                   float* __restrict__ ssq) {
    __shared__ float s[64 * 65];
    __shared__ float part[256];
    int pt = blockIdx.x, b = blockIdx.y, tid = threadIdx.x;
    const float* rb = ref + ((size_t)b * CCH) * LPIX + pt * 64;
    for (int k = 0; k < 16; ++k) {
        int n = tid + 256 * k;           // n = c*64 + p
        int c = n >> 6, p = n & 63;
        s[c * 65 + p] = rb[(size_t)c * LPIX + p];
    }
    __syncthreads();
    {
        int p = tid & 63, g = tid >> 6;
        float acc = 0.f;
        for (int c = g * 16; c < g * 16 + 16; ++c) { float v = s[c * 65 + p]; acc += v * v; }
        part[g * 64 + p] = acc;
    }
    __syncthreads();
    if (tid < 64) {
        float v = part[tid] + part[64 + tid] + part[128 + tid] + part[192 + tid];
        ssq[b * LPIX + pt * 64 + tid] = v;
    }
    float* tb = refT + ((size_t)b * LPIX + pt * 64) * 64;
    for (int k = 0; k < 16; ++k) {
        int n = tid + 256 * k;           // n = p*64 + c
        int p = n >> 6, c = n & 63;
        tb[n] = s[c * 65 + p];
    }
}

// ---- inv[b][p] = 1 / max(sqrt(3x3 box of ssq), 1e-12) --------------------
__global__ __launch_bounds__(256) void invnorm_kernel(const float* __restrict__ ssq,
                                                      float* __restrict__ inv) {
    int t = blockIdx.x * 256 + threadIdx.x;      // over BATCH*LPIX
    int b = t >> 12, p = t & 4095;
    int y = p >> 6, x = p & 63;
    const float* sb = ssq + b * LPIX;
    float n2 = 0.f;
    for (int i = -1; i <= 1; ++i)
        for (int j = -1; j <= 1; ++j) {
            int yy = y + i, xx = x + j;
            if (yy >= 0 && yy < 64 && xx >= 0 && xx < 64) n2 += sb[yy * 64 + xx];
        }
    inv[t] = 1.0f / fmaxf(sqrtf(n2), 1e-12f);
}

// ---- GEMM + x-band epilogue: one wave per 64x64 E-tile -------------------
// v3: K staged in two 32-channel halves through a 32 KiB LDS buffer.
// Channel order 0..63 and FMA body identical to R9 -> bit-identical E.
__global__ __launch_bounds__(256, 2) void gemmE_kernel(const float* __restrict__ ref,
                                                       const float* __restrict__ lr,
                                                       float* __restrict__ E) {
    __shared__ __align__(16) float As[2 * 32 * 64];   // [h][c:32][m:64], 16 KiB
    __shared__ __align__(16) float Bs[2 * 32 * 64];   // [h][c:32][x:64], 16 KiB
    int bx = blockIdx.x, by = blockIdx.y, b = blockIdx.z, tid = threadIdx.x;
    const float* Ab = ref + (size_t)b * CCH * LPIX;
    const float* Bb = lr + (size_t)b * CCH * LPIX;
    int w = tid >> 6, lane = tid & 63, rg = lane >> 3, cg = lane & 7;
    const float* Ap = As + (w >> 1) * 2048 + rg * 8;
    const float* Bp = Bs + (w & 1) * 2048 + cg * 8;
    float acc[8][8] = {};

#pragma unroll
    for (int kh = 0; kh < 2; ++kh) {
        if (kh) __syncthreads();         // WAR: previous half's reads done
        // stage channels kh*32 .. kh*32+31 (1024 f4 = 4 per thread)
#pragma unroll
        for (int kk = 0; kk < 4; ++kk) {
            int n = tid + 256 * kk;      // h = n>>9, c = (n>>4)&31, q = n&15
            int h = n >> 9, c = (n >> 4) & 31, q = n & 15;
            *(float4*)&As[h * 2048 + c * 64 + 4 * q] =
                *(const float4*)&Ab[(size_t)(kh * 32 + c) * LPIX + (2 * by + h) * 64 + 4 * q];
            *(float4*)&Bs[h * 2048 + c * 64 + 4 * q] =
                *(const float4*)&Bb[(size_t)(kh * 32 + c) * LPIX + (2 * bx + h) * 64 + 4 * q];
        }
        __syncthreads();
#pragma unroll 4
        for (int kk = 0; kk < 32; ++kk) {
            float4 a0 = *(const float4*)(Ap + kk * 64);
            float4 a1 = *(const float4*)(Ap + kk * 64 + 4);
            float4 b0 = *(const float4*)(Bp + kk * 64);
            float4 b1 = *(const float4*)(Bp + kk * 64 + 4);
            float av[8] = {a0.x, a0.y, a0.z, a0.w, a1.x, a1.y, a1.z, a1.w};
            float bv[8] = {b0.x, b0.y, b0.z, b0.w, b1.x, b1.y, b1.z, b1.w};
#pragma unroll
            for (int i = 0; i < 8; ++i)
#pragma unroll
                for (int j = 0; j < 8; ++j) acc[i][j] = fmaf(av[i], bv[j], acc[i][j]);
        }
    }

    // x-band epilogue in registers: E[r][c] = D[r-1][c-1] + D[r][c] + D[r+1][c+1]
    float up[7], lf[7], dn[8], rt[8], um, dpc;
#pragma unroll
    for (int t = 0; t < 7; ++t) up[t] = __shfl(acc[7][t], lane - 8, 64);
    um = __shfl(acc[7][7], lane - 9, 64);
#pragma unroll
    for (int t = 0; t < 7; ++t) lf[t] = __shfl(acc[t][7], lane - 1, 64);
#pragma unroll
    for (int t = 1; t < 8; ++t) dn[t] = __shfl(acc[0][t], lane + 8, 64);
    dpc = __shfl(acc[0][0], lane + 9, 64);
#pragma unroll
    for (int t = 1; t < 8; ++t) rt[t] = __shfl(acc[t][0], lane + 1, 64);

    int r1 = 2 * by + (w >> 1), r2 = 2 * bx + (w & 1);
    float* Et = E + ((size_t)b << 24) + ((size_t)((r1 << 6) + r2) << 12) + (rg * 8) * 64 + cg * 8;
    bool rgt = rg > 0, rlt = rg < 7, cgt = cg > 0, clt = cg < 7;
#pragma unroll
    for (int i = 0; i < 8; ++i) {
        float e[8];
#pragma unroll
        for (int j = 0; j < 8; ++j) {
            float dm, dpv;
            if (i >= 1) dm = (j >= 1) ? acc[i - 1][j - 1] : (cgt ? lf[i - 1] : 0.f);
            else        dm = rgt ? ((j >= 1) ? up[j - 1] : (cgt ? um : 0.f)) : 0.f;
            if (i <= 6) dpv = (j <= 6) ? acc[i + 1][j + 1] : (clt ? rt[i + 1] : 0.f);
            else        dpv = rlt ? ((j <= 6) ? dn[j + 1] : (clt ? dpc : 0.f)) : 0.f;
            e[j] = dm + acc[i][j] + dpv;
        }
        *(float4*)(Et + i * 64)     = make_float4(e[0], e[1], e[2], e[3]);
        *(float4*)(Et + i * 64 + 4) = make_float4(e[4], e[5], e[6], e[7]);
    }
}

// ---- band v1: diagonal-segment sweep, register ring of 3 E-tiles (R9) ----
// block (bx=segment, by=k+63, bz=batch); S-tile(y+k, y) = Ea+Eb+Ec elementwise
__global__ __launch_bounds__(256) void band_kernel(const float* __restrict__ E,
                                                   const float* __restrict__ inv,
                                                   u64* __restrict__ packed) {
    __shared__ u64 red[16 * 65];
    int b = blockIdx.z;
    int k = (int)blockIdx.y - 63;
    int t_lo = k < 0 ? -k : 0;
    int t_hi = 64 - (k > 0 ? k : 0);
    int y0 = t_lo + (int)blockIdx.x * 16;
    if (y0 >= t_hi) return;
    int y1 = y0 + 16 < t_hi ? y0 + 16 : t_hi;
    const float* Ebase = E + ((size_t)b << 24);
    const float* invb = inv + b * LPIX;
    u64* pkb = packed + (size_t)b * LPIX;
    int tid = threadIdx.x;
    int c4 = tid & 15, s = tid >> 4;     // cols 4*c4.., x' strata s+16i

    float4 Ea[4], Eb[4], Ec[4];
    auto LOADT = [&](float4* T, int t) {
        if (t >= t_lo && t < t_hi) {
            const float4* tp = (const float4*)(Ebase + ((size_t)(((t + k) << 6) + t) << 12));
#pragma unroll
            for (int i = 0; i < 4; ++i) T[i] = tp[tid + 256 * i];
        } else {
#pragma unroll
            for (int i = 0; i < 4; ++i) T[i] = make_float4(0.f, 0.f, 0.f, 0.f);
        }
    };
    LOADT(Ea, y0 - 1); LOADT(Eb, y0); LOADT(Ec, y0 + 1);

    for (int y = y0; y < y1; ++y) {
        int yprow = (y + k) << 6;        // y' * 64
        u64 kc0 = 0, kc1 = 0, kc2 = 0, kc3 = 0;
#pragma unroll
        for (int i = 0; i < 4; ++i) {
            int xr = s + 16 * i;         // x'
            float iv = invb[yprow + xr];
            int idx = yprow + xr;        // p' = y'*64 + x'
            float vx = (Ea[i].x + Eb[i].x + Ec[i].x) * iv;
            float vy = (Ea[i].y + Eb[i].y + Ec[i].y) * iv;
            float vz = (Ea[i].z + Eb[i].z + Ec[i].z) * iv;
            float vw = (Ea[i].w + Eb[i].w + Ec[i].w) * iv;
            u64 t0 = packKey(vx, idx); kc0 = kc0 > t0 ? kc0 : t0;
            u64 t1 = packKey(vy, idx); kc1 = kc1 > t1 ? kc1 : t1;
            u64 t2 = packKey(vz, idx); kc2 = kc2 > t2 ? kc2 : t2;
            u64 t3 = packKey(vw, idx); kc3 = kc3 > t3 ? kc3 : t3;
        }
        red[s * 65 + 4 * c4 + 0] = kc0;
        red[s * 65 + 4 * c4 + 1] = kc1;
        red[s * 65 + 4 * c4 + 2] = kc2;
        red[s * 65 + 4 * c4 + 3] = kc3;
        __syncthreads();
        if (tid < 64) {
            u64 m = red[tid];
#pragma unroll
            for (int ss = 1; ss < 16; ++ss) {
                u64 v = red[ss * 65 + tid];
                m = m > v ? m : v;
            }
            atomicMax(&pkb[(y << 6) + tid], m);
        }
        __syncthreads();
        if (y + 1 < y1) {
            float4 En[4];
            LOADT(En, y + 2);
#pragma unroll
            for (int i = 0; i < 4; ++i) { Ea[i] = Eb[i]; Eb[i] = Ec[i]; Ec[i] = En[i]; }
        }
    }
}

// ---- gather + fold: one wave per output pixel ----------------------------
__global__ __launch_bounds__(256) void gather_kernel(const u64* __restrict__ packed,
                                                     const float* __restrict__ refT,
                                                     float* __restrict__ Tt) {
    int b = blockIdx.y;
    int wave = threadIdx.x >> 6, lane = threadIdx.x & 63;
    int p = blockIdx.x * 4 + wave;       // 0..4095
    int py = p >> 6, px = p & 63;
    const u64* pk = packed + (size_t)b * LPIX;
    const float* rT = refT + (size_t)b * LPIX * 64;
    float acc = 0.f;
#pragma unroll
    for (int i = 0; i < 3; ++i)
#pragma unroll
        for (int j = 0; j < 3; ++j) {
            int qy = py + 1 - i, qx = px + 1 - j;
            if ((unsigned)qy >= 64u || (unsigned)qx >= 64u) continue;
            int aidx = (int)(~(unsigned int)pk[qy * 64 + qx]);
            int ry = (aidx >> 6) + i - 1, rx = (aidx & 63) + j - 1;
            if ((unsigned)ry >= 64u || (unsigned)rx >= 64u) continue;
            acc += rT[(size_t)(ry * 64 + rx) * 64 + lane];
        }
    Tt[((size_t)b * LPIX + p) * 64 + lane] = acc;
}

// ---- 1x1 conv: z[b][co][p] = w1[co][0:64]*lr + w1[co][64:128]*T + b1 -----
#define XST 36
__global__ __launch_bounds__(256) void conv1_kernel(const float* __restrict__ lr,
                                                    const float* __restrict__ Tt,
                                                    const float* __restrict__ w1,
                                                    const float* __restrict__ b1,
                                                    float* __restrict__ z) {
    __shared__ __align__(16) float xs[128 * XST];
    __shared__ __align__(16) float wsm[64 * 128];
    int pt = blockIdx.x, b = blockIdx.y, tid = threadIdx.x;
    for (int k = 0; k < 8; ++k) {
        int n = tid + 256 * k;           // 2048 float4s of w1
        *(float4*)&wsm[4 * n] = *(const float4*)&w1[4 * n];
    }
    const float* lrb = lr + (size_t)b * CCH * LPIX + pt * 32;
    for (int k = 0; k < 2; ++k) {
        int n = tid + 256 * k;           // 512 f4: c = n>>3, q = n&7
        int c = n >> 3, q = n & 7;
        *(float4*)&xs[c * XST + 4 * q] = *(const float4*)&lrb[(size_t)c * LPIX + 4 * q];
    }
    const float* Tb = Tt + ((size_t)b * LPIX + pt * 32) * 64;
    for (int k = 0; k < 2; ++k) {
        int n = tid + 256 * k;           // 512 f4: p = n>>4, cq = n&15
        int p = n >> 4, cq = n & 15;
        float4 v = *(const float4*)&Tb[p * 64 + 4 * cq];
        xs[(64 + 4 * cq + 0) * XST + p] = v.x;
        xs[(64 + 4 * cq + 1) * XST + p] = v.y;
        xs[(64 + 4 * cq + 2) * XST + p] = v.z;
        xs[(64 + 4 * cq + 3) * XST + p] = v.w;
    }
    __syncthreads();
    int p = tid & 31, g = tid >> 5;      // g: 8 groups of 8 output channels
    float acc[8];
#pragma unroll
    for (int t = 0; t < 8; ++t) acc[t] = b1[g * 8 + t];
    for (int c = 0; c < 128; ++c) {
        float xv = xs[c * XST + p];
#pragma unroll
        for (int t = 0; t < 8; ++t) acc[t] = fmaf(wsm[(g * 8 + t) * 128 + c], xv, acc[t]);
    }
    float* zb = z + (size_t)b * CCH * LPIX + pt * 32;
#pragma unroll
    for (int t = 0; t < 8; ++t) zb[(size_t)(g * 8 + t) * LPIX + p] = acc[t];
}

// ---- depthwise 3x3 + bias + relu -> out ----------------------------------
__global__ __launch_bounds__(256) void dw_kernel(const float* __restrict__ z,
                                                 const float* __restrict__ wd,
                                                 const float* __restrict__ bd,
                                                 float* __restrict__ out) {
    __shared__ __align__(16) float zs[4096];
    int c = blockIdx.x, b = blockIdx.y, tid = threadIdx.x;
    const float* zb = z + ((size_t)b * CCH + c) * LPIX;
    for (int k = 0; k < 4; ++k) {
        int n = tid + 256 * k;
        *(float4*)&zs[4 * n] = *(const float4*)&zb[4 * n];
    }
    __syncthreads();
    float w[9];
#pragma unroll
    for (int t = 0; t < 9; ++t) w[t] = wd[c * 9 + t];
    float bias = bd[c];
    float* ob = out + ((size_t)b * CCH + c) * LPIX;
    for (int s = 0; s < 16; ++s) {
        int p = tid + 256 * s;
        int y = p >> 6, x = p & 63;
        float acc = bias;
#pragma unroll
        for (int i = 0; i < 3; ++i) {
            int yy = y + i - 1;
            if ((unsigned)yy >= 64u) continue;
#pragma unroll
            for (int j = 0; j < 3; ++j) {
                int xx = x + j - 1;
                if ((unsigned)xx >= 64u) continue;
                acc = fmaf(zs[yy * 64 + xx], w[i * 3 + j], acc);
            }
        }
        ob[p] = fmaxf(acc, 0.f);
    }
}

extern "C" void kernel_launch(void* const* d_in, const int* in_sizes, int n_in,
                              void* d_out, int out_size, void* d_ws, size_t ws_size,
                              hipStream_t stream) {
    const float* lr  = (const float*)d_in[0];
    const float* ref = (const float*)d_in[1];
    const float* w1  = (const float*)d_in[2];
    const float* b1  = (const float*)d_in[3];
    const float* wd  = (const float*)d_in[4];
    const float* bd  = (const float*)d_in[5];
    float* out = (float*)d_out;

    float* ws = (float*)d_ws;
    float* refT = ws;                                   // 1,048,576 f
    float* ssq  = refT + (size_t)1048576;               //    16,384 f
    float* inv  = ssq + 16384;                          //    16,384 f
    u64* packed = (u64*)(inv + 16384);                  //    16,384 u64
    float* Tt = (float*)(packed + 16384);               // 1,048,576 f
    float* z  = Tt + (size_t)1048576;                   // 1,048,576 f
    float* E  = z + (size_t)1048576;                    // NB * 16,777,216 f (reused)

    const size_t base = 12845056ull;                    // bytes before E
    const size_t per  = 67108864ull;                    // E bytes per batch
    // NB=2 keeps live E at 128 MiB -> L3-resident for band reads (R9-validated).
    int NB = (ws_size >= base + 2 * per) ? 2 : 1;

    hipMemsetAsync(packed, 0, (size_t)BATCH * LPIX * sizeof(u64), stream);
    prep_kernel<<<dim3(64, BATCH), 256, 0, stream>>>(ref, refT, ssq);
    invnorm_kernel<<<dim3(64), 256, 0, stream>>>(ssq, inv);
    for (int b0 = 0; b0 < BATCH; b0 += NB) {
        gemmE_kernel<<<dim3(32, 32, NB), 256, 0, stream>>>(
            ref + (size_t)b0 * CCH * LPIX, lr + (size_t)b0 * CCH * LPIX, E);
        band_kernel<<<dim3(4, 127, NB), 256, 0, stream>>>(
            E, inv + (size_t)b0 * LPIX, packed + (size_t)b0 * LPIX);
    }
    gather_kernel<<<dim3(1024, BATCH), 256, 0, stream>>>(packed, refT, Tt);
    conv1_kernel<<<dim3(128, BATCH), 256, 0, stream>>>(lr, Tt, w1, b1, z);
    dw_kernel<<<dim3(64, BATCH), 256, 0, stream>>>(z, wd, bd, out);
}